// Round 1
// baseline (335.411 us; speedup 1.0000x reference)
//
#include <hip/hip_runtime.h>
#include <hip/hip_bf16.h>

// DropSphereNd: out = x * keep(n,c) * scale, where keep is derived from a
// rank-16 threshold over activ = embeds @ table per sample row.
// N=64, C=256, H=W=56, EMBED_DIM=16, INDEX=16, scale = 256/240.

#define N_SAMP 64
#define C_CH 256
#define EMBED 16
#define IDX_K 16
#define HW 3136           // 56*56
#define HW4 784           // HW/4

// Kernel 1: compute per-(n,c) multiplier into d_ws.
// One block per sample n (64 blocks), one thread per channel c (256 threads).
__global__ void __launch_bounds__(C_CH)
mask_kernel(const float* __restrict__ embeds, const float* __restrict__ table,
            float* __restrict__ mult) {
    const int n = blockIdx.x;
    const int c = threadIdx.x;

    __shared__ float activ[C_CH];
    __shared__ float thresh;

    // activ[n][c] = sum_k embeds[n][k] * table[k][c]
    float a = 0.0f;
#pragma unroll
    for (int k = 0; k < EMBED; ++k) {
        a += embeds[n * EMBED + k] * table[k * C_CH + c];
    }
    activ[c] = a;
    __syncthreads();

    // Stable rank: #(strictly smaller) + #(equal with lower index).
    // Exactly one thread has rank == IDX_K; its value equals sort(activ)[IDX_K]
    // (robust to ties, matches jnp.sort semantics).
    int cnt = 0;
    for (int j = 0; j < C_CH; ++j) {
        float v = activ[j];
        cnt += (v < a) || (v == a && j < c);
    }
    if (cnt == IDX_K) thresh = a;
    __syncthreads();

    const float scale = (float)C_CH / (float)(C_CH - IDX_K);  // 256/240
    mult[n * C_CH + c] = (thresh <= a) ? scale : 0.0f;
}

// Kernel 2: out = x * mult[plane], vectorized float4. One float4 per thread.
__global__ void __launch_bounds__(256)
scale_kernel(const float4* __restrict__ x, const float* __restrict__ mult,
             float4* __restrict__ out, int total4) {
    const int i = blockIdx.x * blockDim.x + threadIdx.x;
    if (i >= total4) return;
    const int plane = i / HW4;  // (n*C + c)
    const float m = mult[plane];
    float4 v = x[i];
    v.x *= m; v.y *= m; v.z *= m; v.w *= m;
    out[i] = v;
}

extern "C" void kernel_launch(void* const* d_in, const int* in_sizes, int n_in,
                              void* d_out, int out_size, void* d_ws, size_t ws_size,
                              hipStream_t stream) {
    const float* x      = (const float*)d_in[0];   // [64,256,56,56]
    const float* embeds = (const float*)d_in[1];   // [64,16]
    const float* table  = (const float*)d_in[2];   // [16,256]
    float* out = (float*)d_out;
    float* mult = (float*)d_ws;                    // [64,256] floats = 64 KB

    mask_kernel<<<N_SAMP, C_CH, 0, stream>>>(embeds, table, mult);

    const int total4 = (N_SAMP * C_CH * HW) / 4;   // 12,845,056
    const int threads = 256;
    const int blocks = (total4 + threads - 1) / threads;  // 50,176
    scale_kernel<<<blocks, threads, 0, stream>>>((const float4*)x, mult,
                                                 (float4*)out, total4);
}

// Round 3
// 333.589 us; speedup vs baseline: 1.0055x; 1.0055x over previous
//
#include <hip/hip_runtime.h>
#include <hip/hip_bf16.h>

// DropSphereNd: out = x * keep(n,c) * scale, where keep is derived from a
// rank-16 threshold over activ = embeds @ table per sample row.
// N=64, C=256, H=W=56, EMBED_DIM=16, INDEX=16, scale = 256/240.

#define N_SAMP 64
#define C_CH 256
#define EMBED 16
#define IDX_K 16
#define HW 3136           // 56*56
#define HW4 784           // HW/4 (float4 units per plane)

typedef float f32x4 __attribute__((ext_vector_type(4)));  // native vector for nontemporal builtins

// Kernel 1: compute per-(n,c) multiplier into d_ws.
// One block per sample n (64 blocks), one thread per channel c (256 threads).
__global__ void __launch_bounds__(C_CH)
mask_kernel(const float* __restrict__ embeds, const float* __restrict__ table,
            float* __restrict__ mult) {
    const int n = blockIdx.x;
    const int c = threadIdx.x;

    __shared__ float activ[C_CH];
    __shared__ float thresh;

    // activ[n][c] = sum_k embeds[n][k] * table[k][c]
    float a = 0.0f;
#pragma unroll
    for (int k = 0; k < EMBED; ++k) {
        a += embeds[n * EMBED + k] * table[k * C_CH + c];
    }
    activ[c] = a;
    __syncthreads();

    // Stable rank: #(strictly smaller) + #(equal with lower index).
    // Exactly one thread has rank == IDX_K; its value equals sort(activ)[IDX_K]
    // (tie-robust, matches jnp.sort semantics).
    int cnt = 0;
    for (int j = 0; j < C_CH; ++j) {
        float v = activ[j];
        cnt += (v < a) || (v == a && j < c);
    }
    if (cnt == IDX_K) thresh = a;
    __syncthreads();

    const float scale = (float)C_CH / (float)(C_CH - IDX_K);  // 256/240
    mult[n * C_CH + c] = (thresh <= a) ? scale : 0.0f;
}

// Kernel 2: out = x * mult[plane]. 4 float4s per thread, nontemporal
// (read-once / write-once streaming — keep it out of L2/L3).
// total4 = 12,845,056 = 12,544 blocks * 256 threads * 4 — exact, no tail.
__global__ void __launch_bounds__(256)
scale_kernel(const f32x4* __restrict__ x, const float* __restrict__ mult,
             f32x4* __restrict__ out) {
    const unsigned base = blockIdx.x * 1024u + threadIdx.x;
#pragma unroll
    for (int k = 0; k < 4; ++k) {
        const unsigned i = base + k * 256u;
        const unsigned plane = i / HW4;          // (n*C + c), magic-mul
        const float m = mult[plane];
        f32x4 v = __builtin_nontemporal_load(&x[i]);
        v *= m;
        __builtin_nontemporal_store(v, &out[i]);
    }
}

extern "C" void kernel_launch(void* const* d_in, const int* in_sizes, int n_in,
                              void* d_out, int out_size, void* d_ws, size_t ws_size,
                              hipStream_t stream) {
    const float* x      = (const float*)d_in[0];   // [64,256,56,56]
    const float* embeds = (const float*)d_in[1];   // [64,16]
    const float* table  = (const float*)d_in[2];   // [16,256]
    float* out = (float*)d_out;
    float* mult = (float*)d_ws;                    // [64,256] floats = 64 KB

    mask_kernel<<<N_SAMP, C_CH, 0, stream>>>(embeds, table, mult);

    const int total4 = (N_SAMP * C_CH * HW) / 4;   // 12,845,056
    const int blocks = total4 / (256 * 4);         // 12,544 exact
    scale_kernel<<<blocks, 256, 0, stream>>>((const f32x4*)x, mult,
                                             (f32x4*)out);
}